// Round 5
// baseline (1415.487 us; speedup 1.0000x reference)
//
#include <hip/hip_runtime.h>
#include <math.h>

// Problem constants (reference: B,T,D,H = 64,512,256,256)
#define BB 64
#define TT 512
#define DD 256
#define HH 256
// out layout: sequence [B][T][2H] (fwd half | bwd half), then last_state [B][2H]
// last_state[b,:] == sequence[b,T-1,:] (h_last_f = seq_f[T-1], h_first_b = seq_b[T-1])

// ---------------------------------------------------------------------------
// Kernel 1: x_proj = inputs @ W_ih + b, written to BOTH halves of the
// sequence area of d_out (fwd scan consumes+overwrites half 0, bwd half 1).
// M=32768 rows (b*T+t), N=256, K=256.  Workgroup: 256 thr, tile M=64 x N=256.
// Thread (ty,tx): ty=tid/16, tx=tid%16; computes rows ty*4+{0..3},
// cols tx+16*{0..15} (column-interleaved -> conflict-free/broadcast LDS reads).
// ---------------------------------------------------------------------------
__global__ __launch_bounds__(256) void xproj_kernel(
        const float* __restrict__ inp,
        const float* __restrict__ Wih,
        const float* __restrict__ bias,
        float* __restrict__ out) {
    __shared__ float wlds[64 * 256];   // 64 k-rows x 256 cols = 64 KiB
    const int tid = threadIdx.x;
    const int ty = tid >> 4;           // 0..15
    const int tx = tid & 15;           // 0..15
    const int m0 = blockIdx.x * 64;

    float acc[4][16];
    #pragma unroll
    for (int c = 0; c < 16; ++c) {
        float bv = bias[tx + 16 * c];
        #pragma unroll
        for (int r = 0; r < 4; ++r) acc[r][c] = bv;
    }

    for (int kt = 0; kt < 4; ++kt) {
        __syncthreads();               // protect previous tile reads
        // stage W tile [64][256] (Wih rows kt*64 .. kt*64+63)
        const float4* wsrc = (const float4*)(Wih + kt * 64 * 256);
        float4* wdst = (float4*)wlds;
        #pragma unroll
        for (int i = 0; i < 16; ++i) wdst[tid + i * 256] = wsrc[tid + i * 256];
        __syncthreads();

        const float* arow = inp + (size_t)(m0 + ty * 4) * 256 + kt * 64;
        #pragma unroll 4
        for (int kk = 0; kk < 16; ++kk) {
            float4 a0 = *(const float4*)(arow + 0 * 256 + kk * 4);
            float4 a1 = *(const float4*)(arow + 1 * 256 + kk * 4);
            float4 a2 = *(const float4*)(arow + 2 * 256 + kk * 4);
            float4 a3 = *(const float4*)(arow + 3 * 256 + kk * 4);
            #pragma unroll
            for (int q = 0; q < 4; ++q) {
                const float* wrow = wlds + (kk * 4 + q) * 256;
                const float aq0 = (&a0.x)[q];
                const float aq1 = (&a1.x)[q];
                const float aq2 = (&a2.x)[q];
                const float aq3 = (&a3.x)[q];
                #pragma unroll
                for (int c = 0; c < 16; ++c) {
                    const float wv = wrow[tx + 16 * c];   // 16 banks, broadcast over ty
                    acc[0][c] = fmaf(aq0, wv, acc[0][c]);
                    acc[1][c] = fmaf(aq1, wv, acc[1][c]);
                    acc[2][c] = fmaf(aq2, wv, acc[2][c]);
                    acc[3][c] = fmaf(aq3, wv, acc[3][c]);
                }
            }
        }
    }

    // write x_proj duplicated into both halves of the sequence slot
    #pragma unroll
    for (int r = 0; r < 4; ++r) {
        const int m = m0 + ty * 4 + r;
        float* o = out + (size_t)m * 512;
        #pragma unroll
        for (int c = 0; c < 16; ++c) {
            const float v = acc[r][c];
            o[tx + 16 * c] = v;
            o[256 + tx + 16 * c] = v;
        }
    }
}

// ---------------------------------------------------------------------------
// Kernel 2: both scans. 128 workgroups = 64 fwd chains + 64 bwd chains.
// Thread j holds W_hh column j (256 VGPRs, fully unrolled k loop).
// Per step: read xp from own half (prefetched one step ahead),
// h_new = tanh(xp + h . Wcol), overwrite slot with h_new, write carry into
// the OTHER LDS h-buffer -> single barrier per step.
// ---------------------------------------------------------------------------
__global__ __launch_bounds__(256, 1) void scan_kernel(
        const float* __restrict__ mask,
        const float* __restrict__ Whh,
        float* __restrict__ out) {
    __shared__ float hl[2][256];
    const int j = threadIdx.x;
    const int wg = blockIdx.x;
    const int b = wg & 63;
    const bool fwd = (wg < 64);

    // W_hh column j into registers (coalesced per k-row); fully static indexing
    float w[256];
    #pragma unroll
    for (int k = 0; k < 256; ++k) w[k] = Whh[k * 256 + j];

    hl[0][j] = 0.0f;                    // h0 = 0
    __syncthreads();

    float* seq = out + (size_t)b * TT * 512 + (fwd ? 0 : 256);
    float* last = out + (size_t)BB * TT * 512 + (size_t)b * 512 + (fwd ? 0 : 256);
    const float* mrow = mask + b * TT;

    int cur = 0;
    int t = fwd ? 0 : TT - 1;
    float xp = seq[(size_t)t * 512 + j];
    float mv = mrow[t];

    for (int tt = 0; tt < TT; ++tt) {
        // prefetch next step's xp/mask (lands during this step's FMA phase)
        const int tn = fwd ? (tt + 1) : (TT - 2 - tt);
        float xp_n = 0.0f, mv_n = 0.0f;
        if (tt + 1 < TT) {
            xp_n = seq[(size_t)tn * 512 + j];
            mv_n = mrow[tn];
        }

        float a0 = 0.f, a1 = 0.f, a2 = 0.f, a3 = 0.f;
        const float4* h4 = (const float4*)hl[cur];
        #pragma unroll
        for (int k4 = 0; k4 < 64; ++k4) {
            const float4 hv = h4[k4];   // uniform addr -> LDS broadcast
            a0 = fmaf(hv.x, w[4 * k4 + 0], a0);
            a1 = fmaf(hv.y, w[4 * k4 + 1], a1);
            a2 = fmaf(hv.z, w[4 * k4 + 2], a2);
            a3 = fmaf(hv.w, w[4 * k4 + 3], a3);
        }
        const float z = xp + ((a0 + a1) + (a2 + a3));
        // tanh(z) = 1 - 2/(e^{2z}+1); saturates correctly as e^{2z} -> 0 or inf
        const float e = __expf(2.0f * z);
        const float hn = 1.0f - 2.0f * __builtin_amdgcn_rcpf(e + 1.0f);

        seq[(size_t)t * 512 + j] = hn;                 // sequence output (unmasked)
        if (fwd) {
            if (tt == TT - 1) last[j] = hn;            // h_last_f
        } else {
            if (tt == 0) last[j] = hn;                 // h_first_b = seq_b_rev[0]
        }

        const float hc = fwd ? hn : hn * mv;           // bwd carry masked (h0=0)
        hl[cur ^ 1][j] = hc;                           // write OTHER buffer
        __syncthreads();                               // one barrier per step
        cur ^= 1;
        t = tn;
        xp = xp_n;
        mv = mv_n;
    }
}

extern "C" void kernel_launch(void* const* d_in, const int* in_sizes, int n_in,
                              void* d_out, int out_size, void* d_ws, size_t ws_size,
                              hipStream_t stream) {
    const float* inp  = (const float*)d_in[0];   // (B,T,D)
    const float* mask = (const float*)d_in[1];   // (B,T)
    const float* Wih  = (const float*)d_in[2];   // (D,H)
    const float* Whh  = (const float*)d_in[3];   // (H,H)
    const float* bias = (const float*)d_in[4];   // (H,)
    float* out = (float*)d_out;

    // 1) x_proj into both halves of the sequence area (32768/64 = 512 wgs)
    xproj_kernel<<<512, 256, 0, stream>>>(inp, Wih, bias, out);
    // 2) fwd+bwd scans (64+64 wgs), last_state fused
    scan_kernel<<<128, 256, 0, stream>>>(mask, Whh, out);
}

// Round 7
// 676.243 us; speedup vs baseline: 2.0932x; 2.0932x over previous
//
#include <hip/hip_runtime.h>
#include <math.h>

// Problem constants (reference: B,T,D,H = 64,512,256,256)
#define BB 64
#define TT 512
#define DD 256
#define HH 256
// out layout: sequence [B][T][2H] (fwd half | bwd half), then last_state [B][2H]
// last_state[b,:] == sequence[b,T-1,:] (h_last_f = seq_f[T-1], h_first_b = seq_b[T-1])

// ---------------------------------------------------------------------------
// Kernel 1: x_proj = inputs @ W_ih + b, written to BOTH halves of the
// sequence area of d_out (fwd scan consumes+overwrites half 0, bwd half 1).
// Unchanged from round 5 (scan dominates 10:1; one variable at a time).
// ---------------------------------------------------------------------------
__global__ __launch_bounds__(256) void xproj_kernel(
        const float* __restrict__ inp,
        const float* __restrict__ Wih,
        const float* __restrict__ bias,
        float* __restrict__ out) {
    __shared__ float wlds[64 * 256];   // 64 k-rows x 256 cols = 64 KiB
    const int tid = threadIdx.x;
    const int ty = tid >> 4;           // 0..15
    const int tx = tid & 15;           // 0..15
    const int m0 = blockIdx.x * 64;

    float acc[4][16];
    #pragma unroll
    for (int c = 0; c < 16; ++c) {
        float bv = bias[tx + 16 * c];
        #pragma unroll
        for (int r = 0; r < 4; ++r) acc[r][c] = bv;
    }

    for (int kt = 0; kt < 4; ++kt) {
        __syncthreads();               // protect previous tile reads
        const float4* wsrc = (const float4*)(Wih + kt * 64 * 256);
        float4* wdst = (float4*)wlds;
        #pragma unroll
        for (int i = 0; i < 16; ++i) wdst[tid + i * 256] = wsrc[tid + i * 256];
        __syncthreads();

        const float* arow = inp + (size_t)(m0 + ty * 4) * 256 + kt * 64;
        #pragma unroll 4
        for (int kk = 0; kk < 16; ++kk) {
            float4 a0 = *(const float4*)(arow + 0 * 256 + kk * 4);
            float4 a1 = *(const float4*)(arow + 1 * 256 + kk * 4);
            float4 a2 = *(const float4*)(arow + 2 * 256 + kk * 4);
            float4 a3 = *(const float4*)(arow + 3 * 256 + kk * 4);
            #pragma unroll
            for (int q = 0; q < 4; ++q) {
                const float* wrow = wlds + (kk * 4 + q) * 256;
                const float aq0 = (&a0.x)[q];
                const float aq1 = (&a1.x)[q];
                const float aq2 = (&a2.x)[q];
                const float aq3 = (&a3.x)[q];
                #pragma unroll
                for (int c = 0; c < 16; ++c) {
                    const float wv = wrow[tx + 16 * c];
                    acc[0][c] = fmaf(aq0, wv, acc[0][c]);
                    acc[1][c] = fmaf(aq1, wv, acc[1][c]);
                    acc[2][c] = fmaf(aq2, wv, acc[2][c]);
                    acc[3][c] = fmaf(aq3, wv, acc[3][c]);
                }
            }
        }
    }

    #pragma unroll
    for (int r = 0; r < 4; ++r) {
        const int m = m0 + ty * 4 + r;
        float* o = out + (size_t)m * 512;
        #pragma unroll
        for (int c = 0; c < 16; ++c) {
            const float v = acc[r][c];
            o[tx + 16 * c] = v;
            o[256 + tx + 16 * c] = v;
        }
    }
}

// ---------------------------------------------------------------------------
// Kernel 2: both scans. 128 workgroups (64 fwd + 64 bwd chains), 512 threads.
// ANTI-SPILL REDESIGN (r5 post-mortem: VGPR=140 proved w[256] spilled to
// scratch -> 16.8 TB L2 traffic -> 1268us @ VALUBusy 9.7%).
// Thread t: col j = t&255, k-half kh = t>>8. Per-thread weights = 32 float4
// (128 VGPR, 32-trip loops, static indices -> guaranteed promotion).
// Step: partial_kh = h[kh-half] . w  -> part[kh][j] in LDS -> barrier ->
// kh==0 threads: z = xp + p0 + p1, hn = tanh(z), store seq, write h -> barrier.
// ---------------------------------------------------------------------------
__global__ __launch_bounds__(512, 2) void scan_kernel(
        const float* __restrict__ mask,
        const float* __restrict__ Whh,
        float* __restrict__ out) {
    __shared__ float hl[2][256];       // double-buffered hidden state
    __shared__ float part[2][256];     // k-half partial dot products
    const int t = threadIdx.x;
    const int j = t & 255;             // output column
    const int kh = t >> 8;             // k-half: 0 or 1
    const int wg = blockIdx.x;
    const int b = wg & 63;
    const bool fwd = (wg < 64);

    // 128 weights along k for col j: Whh[(kh*128+i)*256 + j].
    // Lane-consecutive j -> each scalar load is a coalesced 256B wave access.
    float4 w4[32];
    {
        const float* wp = Whh + (size_t)(kh * 128) * 256 + j;
        #pragma unroll
        for (int i = 0; i < 32; ++i) {
            float4 v;
            v.x = wp[(4 * i + 0) * 256];
            v.y = wp[(4 * i + 1) * 256];
            v.z = wp[(4 * i + 2) * 256];
            v.w = wp[(4 * i + 3) * 256];
            w4[i] = v;
        }
    }

    if (t < 256) hl[0][t] = 0.0f;      // h0 = 0
    __syncthreads();

    float* seq = out + (size_t)b * TT * 512 + (fwd ? 0 : 256);
    float* last = out + (size_t)BB * TT * 512 + (size_t)b * 512 + (fwd ? 0 : 256);
    const float* mrow = mask + b * TT;

    int cur = 0;
    int tcur = fwd ? 0 : TT - 1;
    float xp = 0.0f, mv = 0.0f;
    if (kh == 0) {                     // only finish-threads need xp/mask
        xp = seq[(size_t)tcur * 512 + j];
        mv = mrow[tcur];
    }

    for (int tt = 0; tt < TT; ++tt) {
        // prefetch next step's xp/mask during this step's FMA phase
        const int tn = fwd ? (tt + 1) : (TT - 2 - tt);
        float xp_n = 0.0f, mv_n = 0.0f;
        if (kh == 0 && tt + 1 < TT) {
            xp_n = seq[(size_t)tn * 512 + j];
            mv_n = mrow[tn];
        }

        // partial dot product over this thread's k-half (uniform-addr LDS
        // float4 reads -> hardware broadcast, conflict-free)
        float a0 = 0.f, a1 = 0.f, a2 = 0.f, a3 = 0.f;
        const float4* h4 = (const float4*)&hl[cur][kh * 128];
        #pragma unroll
        for (int i = 0; i < 32; ++i) {
            const float4 hv = h4[i];
            a0 = fmaf(hv.x, w4[i].x, a0);
            a1 = fmaf(hv.y, w4[i].y, a1);
            a2 = fmaf(hv.z, w4[i].z, a2);
            a3 = fmaf(hv.w, w4[i].w, a3);
        }
        part[kh][j] = (a0 + a1) + (a2 + a3);
        __syncthreads();               // partials visible

        if (kh == 0) {
            const float z = xp + part[0][j] + part[1][j];
            // tanh(z) = 1 - 2/(e^{2z}+1); saturates correctly at +-inf
            const float e = __expf(2.0f * z);
            const float hn = 1.0f - 2.0f * __builtin_amdgcn_rcpf(e + 1.0f);

            seq[(size_t)tcur * 512 + j] = hn;          // sequence out (unmasked)
            if (fwd) {
                if (tt == TT - 1) last[j] = hn;        // h_last_f
            } else {
                if (tt == 0) last[j] = hn;             // h_first_b
            }
            hl[cur ^ 1][j] = fwd ? hn : hn * mv;       // carry (bwd masked, h0=0)
        }
        __syncthreads();               // h ready for next step
        cur ^= 1;
        tcur = tn;
        xp = xp_n;
        mv = mv_n;
    }
}

extern "C" void kernel_launch(void* const* d_in, const int* in_sizes, int n_in,
                              void* d_out, int out_size, void* d_ws, size_t ws_size,
                              hipStream_t stream) {
    const float* inp  = (const float*)d_in[0];   // (B,T,D)
    const float* mask = (const float*)d_in[1];   // (B,T)
    const float* Wih  = (const float*)d_in[2];   // (D,H)
    const float* Whh  = (const float*)d_in[3];   // (H,H)
    const float* bias = (const float*)d_in[4];   // (H,)
    float* out = (float*)d_out;

    // 1) x_proj into both halves of the sequence area (32768/64 = 512 wgs)
    xproj_kernel<<<512, 256, 0, stream>>>(inp, Wih, bias, out);
    // 2) fwd+bwd scans (64+64 wgs x 512 thr), last_state fused
    scan_kernel<<<128, 512, 0, stream>>>(mask, Whh, out);
}

// Round 8
// 674.488 us; speedup vs baseline: 2.0986x; 1.0026x over previous
//
#include <hip/hip_runtime.h>
#include <math.h>

// Problem constants (reference: B,T,D,H = 64,512,256,256)
#define BB 64
#define TT 512
#define DD 256
#define HH 256
// out layout: sequence [B][T][2H] (fwd half | bwd half), then last_state [B][2H]
// last_state[b,:] == sequence[b,T-1,:] (h_last_f = seq_f[T-1], h_first_b = seq_b[T-1])

// ---------------------------------------------------------------------------
// Kernel 1: x_proj = inputs @ W_ih + b, written to BOTH halves of the
// sequence area of d_out. Unchanged (scan still dominates; one variable at a
// time — xproj counters expected in next round's top-5).
// ---------------------------------------------------------------------------
__global__ __launch_bounds__(256) void xproj_kernel(
        const float* __restrict__ inp,
        const float* __restrict__ Wih,
        const float* __restrict__ bias,
        float* __restrict__ out) {
    __shared__ float wlds[64 * 256];   // 64 k-rows x 256 cols = 64 KiB
    const int tid = threadIdx.x;
    const int ty = tid >> 4;           // 0..15
    const int tx = tid & 15;           // 0..15
    const int m0 = blockIdx.x * 64;

    float acc[4][16];
    #pragma unroll
    for (int c = 0; c < 16; ++c) {
        float bv = bias[tx + 16 * c];
        #pragma unroll
        for (int r = 0; r < 4; ++r) acc[r][c] = bv;
    }

    for (int kt = 0; kt < 4; ++kt) {
        __syncthreads();               // protect previous tile reads
        const float4* wsrc = (const float4*)(Wih + kt * 64 * 256);
        float4* wdst = (float4*)wlds;
        #pragma unroll
        for (int i = 0; i < 16; ++i) wdst[tid + i * 256] = wsrc[tid + i * 256];
        __syncthreads();

        const float* arow = inp + (size_t)(m0 + ty * 4) * 256 + kt * 64;
        #pragma unroll 4
        for (int kk = 0; kk < 16; ++kk) {
            float4 a0 = *(const float4*)(arow + 0 * 256 + kk * 4);
            float4 a1 = *(const float4*)(arow + 1 * 256 + kk * 4);
            float4 a2 = *(const float4*)(arow + 2 * 256 + kk * 4);
            float4 a3 = *(const float4*)(arow + 3 * 256 + kk * 4);
            #pragma unroll
            for (int q = 0; q < 4; ++q) {
                const float* wrow = wlds + (kk * 4 + q) * 256;
                const float aq0 = (&a0.x)[q];
                const float aq1 = (&a1.x)[q];
                const float aq2 = (&a2.x)[q];
                const float aq3 = (&a3.x)[q];
                #pragma unroll
                for (int c = 0; c < 16; ++c) {
                    const float wv = wrow[tx + 16 * c];
                    acc[0][c] = fmaf(aq0, wv, acc[0][c]);
                    acc[1][c] = fmaf(aq1, wv, acc[1][c]);
                    acc[2][c] = fmaf(aq2, wv, acc[2][c]);
                    acc[3][c] = fmaf(aq3, wv, acc[3][c]);
                }
            }
        }
    }

    #pragma unroll
    for (int r = 0; r < 4; ++r) {
        const int m = m0 + ty * 4 + r;
        float* o = out + (size_t)m * 512;
        #pragma unroll
        for (int c = 0; c < 16; ++c) {
            const float v = acc[r][c];
            o[tx + 16 * c] = v;
            o[256 + tx + 16 * c] = v;
        }
    }
}

// ---------------------------------------------------------------------------
// Kernel 2: both scans. 128 wgs (64 fwd + 64 bwd), 512 threads.
// r7 post-mortem: float4 w4[32] ARRAY still scratch-allocated (VGPR=92) ->
// 17.2 TB weight re-fetch -> L2-BW-bound at 32.5 TB/s (529us).
// FIX: 32 NAMED float4 variables (SSA values, cannot be scratch-allocated;
// spill only under true pressure: need ~170 < cap 256 at launch_bounds 512,2).
// Everything else identical to r7.
// ---------------------------------------------------------------------------
#define REP32(M) M(0)M(1)M(2)M(3)M(4)M(5)M(6)M(7)M(8)M(9)M(10)M(11)M(12)M(13)M(14)M(15)M(16)M(17)M(18)M(19)M(20)M(21)M(22)M(23)M(24)M(25)M(26)M(27)M(28)M(29)M(30)M(31)

__global__ __launch_bounds__(512, 2) void scan_kernel(
        const float* __restrict__ mask,
        const float* __restrict__ Whh,
        float* __restrict__ out) {
    __shared__ float hl[2][256];       // double-buffered hidden state
    __shared__ float part[2][256];     // k-half partial dot products
    const int t = threadIdx.x;
    const int j = t & 255;             // output column
    const int kh = t >> 8;             // k-half: 0 or 1
    const int wg = blockIdx.x;
    const int b = wg & 63;
    const bool fwd = (wg < 64);

    // 128 weights along k for col j, in 32 NAMED float4 registers.
    // Whh[(kh*128 + 4i+q)*256 + j]; lane-consecutive j -> coalesced loads.
#define DECLW(i) float4 w##i;
    REP32(DECLW)
    {
        const float* wp = Whh + (size_t)(kh * 128) * 256 + j;
#define LOADW(i) \
        w##i.x = wp[(4*(i)+0)*256]; \
        w##i.y = wp[(4*(i)+1)*256]; \
        w##i.z = wp[(4*(i)+2)*256]; \
        w##i.w = wp[(4*(i)+3)*256];
        REP32(LOADW)
    }

    if (t < 256) hl[0][t] = 0.0f;      // h0 = 0
    __syncthreads();

    float* seq = out + (size_t)b * TT * 512 + (fwd ? 0 : 256);
    float* last = out + (size_t)BB * TT * 512 + (size_t)b * 512 + (fwd ? 0 : 256);
    const float* mrow = mask + b * TT;

    int cur = 0;
    int tcur = fwd ? 0 : TT - 1;
    float xp = 0.0f, mv = 0.0f;
    if (kh == 0) {                     // only finish-threads need xp/mask
        xp = seq[(size_t)tcur * 512 + j];
        mv = mrow[tcur];
    }

    for (int tt = 0; tt < TT; ++tt) {
        // prefetch next step's xp/mask during this step's FMA phase
        const int tn = fwd ? (tt + 1) : (TT - 2 - tt);
        float xp_n = 0.0f, mv_n = 0.0f;
        if (kh == 0 && tt + 1 < TT) {
            xp_n = seq[(size_t)tn * 512 + j];
            mv_n = mrow[tn];
        }

        // partial dot over this thread's k-half; uniform-addr float4 LDS
        // reads (hardware broadcast, conflict-free), static offsets.
        float a0 = 0.f, a1 = 0.f, a2 = 0.f, a3 = 0.f;
        const float4* h4 = (const float4*)&hl[cur][kh * 128];
#define FMAW(i) { const float4 hv = h4[i]; \
        a0 = fmaf(hv.x, w##i.x, a0); \
        a1 = fmaf(hv.y, w##i.y, a1); \
        a2 = fmaf(hv.z, w##i.z, a2); \
        a3 = fmaf(hv.w, w##i.w, a3); }
        REP32(FMAW)
        part[kh][j] = (a0 + a1) + (a2 + a3);
        __syncthreads();               // partials visible

        if (kh == 0) {
            const float z = xp + part[0][j] + part[1][j];
            // tanh(z) = 1 - 2/(e^{2z}+1); saturates correctly at +-inf
            const float e = __expf(2.0f * z);
            const float hn = 1.0f - 2.0f * __builtin_amdgcn_rcpf(e + 1.0f);

            seq[(size_t)tcur * 512 + j] = hn;          // sequence out (unmasked)
            if (fwd) {
                if (tt == TT - 1) last[j] = hn;        // h_last_f
            } else {
                if (tt == 0) last[j] = hn;             // h_first_b
            }
            hl[cur ^ 1][j] = fwd ? hn : hn * mv;       // carry (bwd masked, h0=0)
        }
        __syncthreads();               // h ready for next step
        cur ^= 1;
        tcur = tn;
        xp = xp_n;
        mv = mv_n;
    }
}

extern "C" void kernel_launch(void* const* d_in, const int* in_sizes, int n_in,
                              void* d_out, int out_size, void* d_ws, size_t ws_size,
                              hipStream_t stream) {
    const float* inp  = (const float*)d_in[0];   // (B,T,D)
    const float* mask = (const float*)d_in[1];   // (B,T)
    const float* Wih  = (const float*)d_in[2];   // (D,H)
    const float* Whh  = (const float*)d_in[3];   // (H,H)
    const float* bias = (const float*)d_in[4];   // (H,)
    float* out = (float*)d_out;

    // 1) x_proj into both halves of the sequence area (32768/64 = 512 wgs)
    xproj_kernel<<<512, 256, 0, stream>>>(inp, Wih, bias, out);
    // 2) fwd+bwd scans (64+64 wgs x 512 thr), last_state fused
    scan_kernel<<<128, 512, 0, stream>>>(mask, Whh, out);
}

// Round 9
// 541.690 us; speedup vs baseline: 2.6131x; 1.2452x over previous
//
#include <hip/hip_runtime.h>
#include <math.h>

// Problem constants (reference: B,T,D,H = 64,512,256,256)
#define BB 64
#define TT 512
#define DD 256
#define HH 256
// out layout: sequence [B][T][2H] (fwd half | bwd half), then last_state [B][2H]

// ---------------------------------------------------------------------------
// Kernel 1: x_proj = inputs @ W_ih + b -> both halves of sequence area.
// Unchanged (separate dispatch; ~143us; next target after scan).
// ---------------------------------------------------------------------------
__global__ __launch_bounds__(256) void xproj_kernel(
        const float* __restrict__ inp,
        const float* __restrict__ Wih,
        const float* __restrict__ bias,
        float* __restrict__ out) {
    __shared__ float wlds[64 * 256];   // 64 k-rows x 256 cols = 64 KiB
    const int tid = threadIdx.x;
    const int ty = tid >> 4;           // 0..15
    const int tx = tid & 15;           // 0..15
    const int m0 = blockIdx.x * 64;

    float acc[4][16];
    #pragma unroll
    for (int c = 0; c < 16; ++c) {
        float bv = bias[tx + 16 * c];
        #pragma unroll
        for (int r = 0; r < 4; ++r) acc[r][c] = bv;
    }

    for (int kt = 0; kt < 4; ++kt) {
        __syncthreads();
        const float4* wsrc = (const float4*)(Wih + kt * 64 * 256);
        float4* wdst = (float4*)wlds;
        #pragma unroll
        for (int i = 0; i < 16; ++i) wdst[tid + i * 256] = wsrc[tid + i * 256];
        __syncthreads();

        const float* arow = inp + (size_t)(m0 + ty * 4) * 256 + kt * 64;
        #pragma unroll 4
        for (int kk = 0; kk < 16; ++kk) {
            float4 a0 = *(const float4*)(arow + 0 * 256 + kk * 4);
            float4 a1 = *(const float4*)(arow + 1 * 256 + kk * 4);
            float4 a2 = *(const float4*)(arow + 2 * 256 + kk * 4);
            float4 a3 = *(const float4*)(arow + 3 * 256 + kk * 4);
            #pragma unroll
            for (int q = 0; q < 4; ++q) {
                const float* wrow = wlds + (kk * 4 + q) * 256;
                const float aq0 = (&a0.x)[q];
                const float aq1 = (&a1.x)[q];
                const float aq2 = (&a2.x)[q];
                const float aq3 = (&a3.x)[q];
                #pragma unroll
                for (int c = 0; c < 16; ++c) {
                    const float wv = wrow[tx + 16 * c];
                    acc[0][c] = fmaf(aq0, wv, acc[0][c]);
                    acc[1][c] = fmaf(aq1, wv, acc[1][c]);
                    acc[2][c] = fmaf(aq2, wv, acc[2][c]);
                    acc[3][c] = fmaf(aq3, wv, acc[3][c]);
                }
            }
        }
    }

    #pragma unroll
    for (int r = 0; r < 4; ++r) {
        const int m = m0 + ty * 4 + r;
        float* o = out + (size_t)m * 512;
        #pragma unroll
        for (int c = 0; c < 16; ++c) {
            const float v = acc[r][c];
            o[tx + 16 * c] = v;
            o[256 + tx + 16 * c] = v;
        }
    }
}

// ---------------------------------------------------------------------------
// Kernel 2: both scans. 128 wgs (64 fwd + 64 bwd), 512 threads, 1 chain/wg.
// r8 post-mortem: two co-binding ceilings at ~105 B/cyc/CU:
//   (a) weights never register-resident (VGPR=92) -> L2 refetch 256KB/step/CU
//   (b) h-broadcast: 256 uniform ds_read_b128/step/CU -> 256KB/step LDS
//       register-writeback (broadcast is NOT free at b128 width).
// FIXES:
//   (a) 128 NAMED floats + asm volatile ""(+v) opaque pins (loads cannot be
//       sunk/re-rolled; allocator must keep in VGPR or spill) +
//       amdgpu_waves_per_eu(2,2) (occupancy target 2 -> 256 VGPR budget).
//   (b) repartition: thread (kq=t>>6, cg=t&63) owns cols {cg,cg+64,cg+128,
//       cg+192} x k-range [32kq,32kq+32): each h-quad read feeds 16 FMAs
//       (was 4) -> 64 broadcast b128/chain-step (was 256). 8-way k-partials
//       via part[8][256]; single hl buffer (barriers make dbuf unneeded).
// ---------------------------------------------------------------------------
#define R8C(M, c) M(c,0) M(c,1) M(c,2) M(c,3) M(c,4) M(c,5) M(c,6) M(c,7)

#define DECL_LOAD(c, i) \
    float w##c##_##i##_0 = wp##c[(4*(i)+0)*256]; \
    float w##c##_##i##_1 = wp##c[(4*(i)+1)*256]; \
    float w##c##_##i##_2 = wp##c[(4*(i)+2)*256]; \
    float w##c##_##i##_3 = wp##c[(4*(i)+3)*256];

#define PIN(c, i) \
    asm volatile("" : "+v"(w##c##_##i##_0), "+v"(w##c##_##i##_1), \
                      "+v"(w##c##_##i##_2), "+v"(w##c##_##i##_3));

#define FMAQ(c, i) \
    acc##c = fmaf(hv.x, w##c##_##i##_0, acc##c); \
    acc##c = fmaf(hv.y, w##c##_##i##_1, acc##c); \
    acc##c = fmaf(hv.z, w##c##_##i##_2, acc##c); \
    acc##c = fmaf(hv.w, w##c##_##i##_3, acc##c);

#define STEPQ(unused, i) { const float4 hv = h4[i]; FMAQ(0,i) FMAQ(1,i) FMAQ(2,i) FMAQ(3,i) }

__global__ __launch_bounds__(512)
__attribute__((amdgpu_waves_per_eu(2, 2)))
void scan_kernel(
        const float* __restrict__ mask,
        const float* __restrict__ Whh,
        float* __restrict__ out) {
    __shared__ float hl[256];          // hidden state (single buffer)
    __shared__ float part[8][256];     // k-partials
    const int t = threadIdx.x;
    const int cg = t & 63;             // column group (4 cols: cg+64c)
    const int kq = t >> 6;             // k-slice 0..7 -> k in [32kq, 32kq+32)
    const int wg = blockIdx.x;
    const int b = wg & 63;
    const bool fwd = (wg < 64);

    // weight pointers: col cg+64c, k-rows 32kq..32kq+31 (lane-consecutive cg
    // -> coalesced). 128 named floats, pinned to VGPRs below.
    const float* wp0 = Whh + (size_t)(kq * 32) * 256 + cg;
    const float* wp1 = wp0 + 64;
    const float* wp2 = wp0 + 128;
    const float* wp3 = wp0 + 192;
    R8C(DECL_LOAD, 0) R8C(DECL_LOAD, 1) R8C(DECL_LOAD, 2) R8C(DECL_LOAD, 3)
    R8C(PIN, 0) R8C(PIN, 1) R8C(PIN, 2) R8C(PIN, 3)

    if (t < 256) hl[t] = 0.0f;         // h0 = 0
    __syncthreads();

    float* seq = out + (size_t)b * TT * 512 + (fwd ? 0 : 256);
    float* last = out + (size_t)BB * TT * 512 + (size_t)b * 512 + (fwd ? 0 : 256);
    const float* mrow = mask + b * TT;

    int tcur = fwd ? 0 : TT - 1;
    float xp = 0.0f, mv = 0.0f;
    if (t < 256) {                     // finish threads (j = t)
        xp = seq[(size_t)tcur * 512 + t];
        mv = mrow[tcur];
    }

    const float4* h4 = (const float4*)(hl + kq * 32);

    #pragma unroll 1
    for (int tt = 0; tt < TT; ++tt) {
        const int tn = fwd ? (tt + 1) : (TT - 2 - tt);
        float xp_n = 0.0f, mv_n = 0.0f;
        if (t < 256 && tt + 1 < TT) {  // prefetch lands under FMA phase
            xp_n = seq[(size_t)tn * 512 + t];
            mv_n = mrow[tn];
        }

        // 8 broadcast b128 reads feed 128 FMAs (16 per read)
        float acc0 = 0.f, acc1 = 0.f, acc2 = 0.f, acc3 = 0.f;
        R8C(STEPQ, x)

        part[kq][cg]       = acc0;
        part[kq][cg + 64]  = acc1;
        part[kq][cg + 128] = acc2;
        part[kq][cg + 192] = acc3;
        __syncthreads();               // partials visible

        if (t < 256) {
            const int j = t;
            const float s01 = part[0][j] + part[1][j];
            const float s23 = part[2][j] + part[3][j];
            const float s45 = part[4][j] + part[5][j];
            const float s67 = part[6][j] + part[7][j];
            const float z = xp + ((s01 + s23) + (s45 + s67));
            // tanh(z) = 1 - 2/(e^{2z}+1); saturates correctly at +-inf
            const float e = __expf(2.0f * z);
            const float hn = 1.0f - 2.0f * __builtin_amdgcn_rcpf(e + 1.0f);

            seq[(size_t)tcur * 512 + j] = hn;          // sequence (unmasked)
            if (fwd) {
                if (tt == TT - 1) last[j] = hn;        // h_last_f
            } else {
                if (tt == 0) last[j] = hn;             // h_first_b
            }
            hl[j] = fwd ? hn : hn * mv;                // carry (bwd masked)
        }
        __syncthreads();               // h ready for next step
        tcur = tn;
        xp = xp_n;
        mv = mv_n;
    }
}

extern "C" void kernel_launch(void* const* d_in, const int* in_sizes, int n_in,
                              void* d_out, int out_size, void* d_ws, size_t ws_size,
                              hipStream_t stream) {
    const float* inp  = (const float*)d_in[0];   // (B,T,D)
    const float* mask = (const float*)d_in[1];   // (B,T)
    const float* Wih  = (const float*)d_in[2];   // (D,H)
    const float* Whh  = (const float*)d_in[3];   // (H,H)
    const float* bias = (const float*)d_in[4];   // (H,)
    float* out = (float*)d_out;

    xproj_kernel<<<512, 256, 0, stream>>>(inp, Wih, bias, out);
    scan_kernel<<<128, 512, 0, stream>>>(mask, Whh, out);
}